// Round 17
// baseline (1120.861 us; speedup 1.0000x reference)
//
#include <hip/hip_runtime.h>

typedef __attribute__((ext_vector_type(4))) float  f32x4;
typedef __attribute__((ext_vector_type(2))) float  f32x2;
typedef __attribute__((ext_vector_type(8))) __bf16 bf16x8;
typedef __attribute__((ext_vector_type(4))) short  s16x4;
typedef __attribute__((ext_vector_type(8))) short  s16x8;
typedef unsigned char uchar;

__device__ __forceinline__ unsigned short f2bf(float f) {
  unsigned u = __builtin_bit_cast(unsigned, f);
  u += 0x7FFFu + ((u >> 16) & 1u);
  return (unsigned short)(u >> 16);
}
__device__ __forceinline__ float b2f(short s) {
  return __builtin_bit_cast(float, (unsigned)((unsigned short)s) << 16);
}
// sigmoid-form gelu: ~4 VALU ops
__device__ __forceinline__ float gelu_sig(float v) {
  float t = __expf(-1.702f * v);
  return v * __builtin_amdgcn_rcpf(1.f + t);
}

__device__ __forceinline__ void gload16(const void* g, void* l) {
  __builtin_amdgcn_global_load_lds(
      (const __attribute__((address_space(1))) void*)g,
      (__attribute__((address_space(3))) void*)l, 16, 0, 0);
}

// in_x f32 -> xb bf16 (once)
__global__ __launch_bounds__(256) void x2bf(const float* __restrict__ x,
                                            short* __restrict__ xb) {
  int i = blockIdx.x * 256 + threadIdx.x;
  float4 v = *(const float4*)(x + (size_t)i * 4);
  s16x4 o;
  o[0] = (short)f2bf(v.x);
  o[1] = (short)f2bf(v.y);
  o[2] = (short)f2bf(v.z);
  o[3] = (short)f2bf(v.w);
  *(s16x4*)(xb + (size_t)i * 4) = o;
}

// Transpose + cast weights: W [L][In][Out] f32 -> WT [L][Out][In] bf16
__global__ __launch_bounds__(256) void wcast(const float* __restrict__ W,
                                             short* __restrict__ WT,
                                             int In, int Out) {
  int i = blockIdx.x * 256 + threadIdx.x;
  int lay = blockIdx.y;
  if (i >= In * Out) return;
  const float* w = W + (size_t)lay * In * Out;
  short* wt = WT + (size_t)lay * In * Out;
  int ii = i % In, oo = i / In;
  wt[(size_t)oo * In + ii] = (short)f2bf(w[(size_t)ii * Out + oo]);
}

// LayerNorm over C=256, bf16 in -> bf16 out (used once, layer-0 ln1)
__global__ __launch_bounds__(256) void ln_k(const short* __restrict__ xb,
                                            const float* __restrict__ g,
                                            const float* __restrict__ b,
                                            short* __restrict__ out) {
  int row = blockIdx.x * 4 + (threadIdx.x >> 6);
  int l = threadIdx.x & 63;
  const s16x4 vb = *(const s16x4*)(xb + (size_t)row * 256 + l * 4);
  float v0 = b2f(vb[0]), v1 = b2f(vb[1]), v2 = b2f(vb[2]), v3 = b2f(vb[3]);
  float s  = v0 + v1 + v2 + v3;
  float ss = v0 * v0 + v1 * v1 + v2 * v2 + v3 * v3;
#pragma unroll
  for (int o = 32; o >= 1; o >>= 1) {
    s  += __shfl_xor(s, o);
    ss += __shfl_xor(ss, o);
  }
  float mean = s * (1.0f / 256.0f);
  float var  = ss * (1.0f / 256.0f) - mean * mean;
  float rstd = rsqrtf(var + 1e-5f);
  const float4 gg = *(const float4*)(g + l * 4);
  const float4 bb = *(const float4*)(b + l * 4);
  s16x4 o4;
  o4[0] = (short)f2bf((v0 - mean) * rstd * gg.x + bb.x);
  o4[1] = (short)f2bf((v1 - mean) * rstd * gg.y + bb.y);
  o4[2] = (short)f2bf((v2 - mean) * rstd * gg.z + bb.z);
  o4[3] = (short)f2bf((v3 - mean) * rstd * gg.w + bb.w);
  *(s16x4*)(out + (size_t)row * 256 + l * 4) = o4;
}

// KNN attention: one wave per point. q bf16 [N][256], k8/v8 fp8 [N][256]
__global__ __launch_bounds__(256) void attn_k(const short* __restrict__ q_,
                                              const uchar* __restrict__ k8,
                                              const uchar* __restrict__ v8,
                                              const int* __restrict__ knn,
                                              short* __restrict__ out) {
  int n = blockIdx.x * 4 + (threadIdx.x >> 6);
  int l = threadIdx.x & 63;
  int j = l & 15, g = l >> 4;
  int idxj = knn[(size_t)n * 16 + j];
  const short* qp = q_ + (size_t)n * 256 + g * 64;
  const uchar* kp = k8 + (size_t)idxj * 256 + g * 64;
  float partial = 0.f;
#pragma unroll
  for (int t = 0; t < 4; ++t) {  // 16 channels per t
    int4 kv = *(const int4*)(kp + t * 16);
    s16x8 q0 = *(const s16x8*)(qp + t * 16);
    s16x8 q1 = *(const s16x8*)(qp + t * 16 + 8);
    f32x2 a;
    a = __builtin_amdgcn_cvt_pk_f32_fp8(kv.x, false);
    partial += a[0] * b2f(q0[0]) + a[1] * b2f(q0[1]);
    a = __builtin_amdgcn_cvt_pk_f32_fp8(kv.x, true);
    partial += a[0] * b2f(q0[2]) + a[1] * b2f(q0[3]);
    a = __builtin_amdgcn_cvt_pk_f32_fp8(kv.y, false);
    partial += a[0] * b2f(q0[4]) + a[1] * b2f(q0[5]);
    a = __builtin_amdgcn_cvt_pk_f32_fp8(kv.y, true);
    partial += a[0] * b2f(q0[6]) + a[1] * b2f(q0[7]);
    a = __builtin_amdgcn_cvt_pk_f32_fp8(kv.z, false);
    partial += a[0] * b2f(q1[0]) + a[1] * b2f(q1[1]);
    a = __builtin_amdgcn_cvt_pk_f32_fp8(kv.z, true);
    partial += a[0] * b2f(q1[2]) + a[1] * b2f(q1[3]);
    a = __builtin_amdgcn_cvt_pk_f32_fp8(kv.w, false);
    partial += a[0] * b2f(q1[4]) + a[1] * b2f(q1[5]);
    a = __builtin_amdgcn_cvt_pk_f32_fp8(kv.w, true);
    partial += a[0] * b2f(q1[6]) + a[1] * b2f(q1[7]);
  }
  partial += __shfl_xor(partial, 16);
  partial += __shfl_xor(partial, 32);
  float score = partial * 0.0625f;  // C^-0.5, C=256
  float mx = score;
#pragma unroll
  for (int o = 1; o < 16; o <<= 1) mx = fmaxf(mx, __shfl_xor(mx, o));
  float e = __expf(score - mx);
  float sum = e;
#pragma unroll
  for (int o = 1; o < 16; o <<= 1) sum += __shfl_xor(sum, o);
  float attn = e / sum;
  float4 o4 = {0.f, 0.f, 0.f, 0.f};
#pragma unroll
  for (int jj = 0; jj < 16; ++jj) {
    float aj = __shfl(attn, jj);
    int   ij = __shfl(idxj, jj);
    int vv = *(const int*)(v8 + (size_t)ij * 256 + l * 4);
    f32x2 lo = __builtin_amdgcn_cvt_pk_f32_fp8(vv, false);
    f32x2 hi = __builtin_amdgcn_cvt_pk_f32_fp8(vv, true);
    o4.x += aj * lo[0];
    o4.y += aj * lo[1];
    o4.z += aj * hi[0];
    o4.w += aj * hi[1];
  }
  s16x4 ob;
  ob[0] = (short)f2bf(o4.x);
  ob[1] = (short)f2bf(o4.y);
  ob[2] = (short)f2bf(o4.z);
  ob[3] = (short)f2bf(o4.w);
  *(s16x4*)(out + (size_t)n * 256 + l * 4) = ob;
}

// GEMM: A [M][KD] bf16 x BT [Nout][KD] bf16 -> out [M][Nout]
// EPI 4: +bias +resid(bf16) -> f32 (final layer).
// EPI 2: +bias, sigmoid-gelu -> bf16 (LDS-transpose, s16x8 stores).
// EPI 3: qkv split -> q bf16 / k8 fp8 / v8 fp8 (LDS-transpose epilogue).
// 128x128 tile, BK=64, 4 waves (2x2), T2 XOR swizzle, T1 XCD-chunked swizzle.
template <int EPI, int KD>
__global__ __launch_bounds__(256) void gemm_k(
    const short* __restrict__ A, const short* __restrict__ BT,
    const float* __restrict__ bias, const short* __restrict__ residb,
    short* __restrict__ outb, float* __restrict__ outf,
    uchar* __restrict__ k8, uchar* __restrict__ v8, int Nout, int gx) {
  __shared__ __align__(16) char pool[36864];
  short* lA = (short*)pool;
  short* lB = (short*)(pool + 16384);
  const int tid = threadIdx.x;
  const int l = tid & 63, w = tid >> 6;
  const int nwg = gridDim.x;
  const int bid = blockIdx.x;
  const int swz = (bid & 7) * (nwg >> 3) + (bid >> 3);
  const int m0 = (swz / gx) << 7, n0 = (swz % gx) << 7;
  const int wm = w >> 1, wn = w & 1;

  f32x4 acc[4][4];
#pragma unroll
  for (int i = 0; i < 4; ++i)
#pragma unroll
    for (int jj = 0; jj < 4; ++jj) acc[i][jj] = f32x4{0.f, 0.f, 0.f, 0.f};

  const int srow = (w << 3) + (l >> 3);
  const int scol = (((l & 7) << 3)) ^ ((srow & 7) << 3);
  const short* gA = A + (size_t)(m0 + srow) * KD + scol;
  const short* gB = BT + (size_t)(n0 + srow) * KD + scol;

  for (int kt = 0; kt < KD; kt += 64) {
#pragma unroll
    for (int it = 0; it < 4; ++it) {
      gload16(gA + (size_t)(it * 32) * KD + kt, &lA[(it * 32 + w * 8) * 64]);
      gload16(gB + (size_t)(it * 32) * KD + kt, &lB[(it * 32 + w * 8) * 64]);
    }
    __syncthreads();
#pragma unroll
    for (int kc = 0; kc < 2; ++kc) {
      bf16x8 aF[4], bF[4];
#pragma unroll
      for (int f = 0; f < 4; ++f) {
        int r = wm * 64 + f * 16 + (l & 15);
        int ce = (kc * 32 + ((l >> 4) << 3)) ^ ((r & 7) << 3);
        aF[f] = *(const bf16x8*)(lA + r * 64 + ce);
      }
#pragma unroll
      for (int f = 0; f < 4; ++f) {
        int r = wn * 64 + f * 16 + (l & 15);
        int ce = (kc * 32 + ((l >> 4) << 3)) ^ ((r & 7) << 3);
        bF[f] = *(const bf16x8*)(lB + r * 64 + ce);
      }
#pragma unroll
      for (int mf = 0; mf < 4; ++mf)
#pragma unroll
        for (int nf = 0; nf < 4; ++nf)
          acc[mf][nf] = __builtin_amdgcn_mfma_f32_16x16x32_bf16(
              aF[mf], bF[nf], acc[mf][nf], 0, 0, 0);
    }
    __syncthreads();
  }

  const int lr = (l >> 4) << 2, lc = l & 15;
  if (EPI == 4) {
#pragma unroll
    for (int mf = 0; mf < 4; ++mf) {
#pragma unroll
      for (int nf = 0; nf < 4; ++nf) {
#pragma unroll
        for (int jj = 0; jj < 4; ++jj) {
          int row = m0 + wm * 64 + mf * 16 + lr + jj;
          int col = n0 + wn * 64 + nf * 16 + lc;
          float v = acc[mf][nf][jj] + bias[col] +
                    b2f(residb[(size_t)row * 256 + col]);
          outf[(size_t)row * 256 + col] = v;
        }
      }
    }
    return;
  }

  // EPI 2/3: wave-private LDS transpose -> coalesced stores.
  short* myL = (short*)(pool + w * 9216);
#pragma unroll
  for (int mf = 0; mf < 4; ++mf) {
#pragma unroll
    for (int nf = 0; nf < 4; ++nf) {
#pragma unroll
      for (int jj = 0; jj < 4; ++jj) {
        int rl = mf * 16 + lr + jj;
        int cl = nf * 16 + lc;
        float v = acc[mf][nf][jj];
        if (EPI == 2) v = gelu_sig(v + bias[n0 + wn * 64 + cl]);
        myL[rl * 72 + cl] = (short)f2bf(v);
      }
    }
  }
#pragma unroll
  for (int it = 0; it < 8; ++it) {
    int rl = it * 8 + (l >> 3);
    int cl = (l & 7) * 8;
    s16x8 vv = *(const s16x8*)(myL + rl * 72 + cl);
    int rowg = m0 + wm * 64 + rl;
    int colg = n0 + wn * 64 + cl;
    if (EPI == 2) {
      *(s16x8*)(outb + (size_t)rowg * Nout + colg) = vv;
    } else {  // EPI 3: qkv split
      if (colg < 256) {
        *(s16x8*)(outb + (size_t)rowg * 256 + colg) = vv;
      } else {
        unsigned w0 = __builtin_amdgcn_cvt_pk_fp8_f32(b2f(vv[0]), b2f(vv[1]), 0, false);
        w0 = __builtin_amdgcn_cvt_pk_fp8_f32(b2f(vv[2]), b2f(vv[3]), w0, true);
        unsigned w1 = __builtin_amdgcn_cvt_pk_fp8_f32(b2f(vv[4]), b2f(vv[5]), 0, false);
        w1 = __builtin_amdgcn_cvt_pk_fp8_f32(b2f(vv[6]), b2f(vv[7]), w1, true);
        int2 pk = make_int2((int)w0, (int)w1);
        uchar* dst = (colg < 512) ? (k8 + (size_t)rowg * 256 + (colg - 256))
                                  : (v8 + (size_t)rowg * 256 + (colg - 512));
        *(int2*)dst = pk;
      }
    }
  }
}

// GEMM + bias + resid + fused LayerNorm, v3: 128x256 tile, 8 waves (2x4),
// each wave 64x64 = acc[4][4] (same per-wave shape as proven gemm_k).
// Writes xb (bf16 residual stream) and act = LN(xb) bf16.
template <int KD>
__global__ __launch_bounds__(512) void gemm_ln(
    const short* __restrict__ A, const short* __restrict__ BT,
    const float* __restrict__ bias, const short* __restrict__ residb,
    short* __restrict__ xbout, const float* __restrict__ lng,
    const float* __restrict__ lnb, short* __restrict__ actout) {
  __shared__ __align__(16) short lA[128 * 64];   // 16 KB
  __shared__ __align__(16) short lB[256 * 64];   // 32 KB
  __shared__ float psum[4][128], psq[4][128];    // 4 KB
  const int tid = threadIdx.x;
  const int l = tid & 63, w = tid >> 6;  // w in 0..7
  const int nwg = gridDim.x;             // 512
  const int bid = blockIdx.x;
  const int swz = (bid & 7) * (nwg >> 3) + (bid >> 3);
  const int m0 = swz << 7;
  const int wm = w >> 2, wn = w & 3;

  f32x4 acc[4][4];
#pragma unroll
  for (int i = 0; i < 4; ++i)
#pragma unroll
    for (int jj = 0; jj < 4; ++jj) acc[i][jj] = f32x4{0.f, 0.f, 0.f, 0.f};

  const int srow = (w << 3) + (l >> 3);                   // 0..63
  const int scol = (((l & 7) << 3)) ^ ((srow & 7) << 3);
  const short* gA = A + (size_t)(m0 + srow) * KD + scol;
  const short* gB = BT + (size_t)srow * KD + scol;

  for (int kt = 0; kt < KD; kt += 64) {
#pragma unroll
    for (int it = 0; it < 2; ++it)
      gload16(gA + (size_t)(it * 64) * KD + kt, &lA[(it * 64 + w * 8) * 64]);
#pragma unroll
    for (int it = 0; it < 4; ++it)
      gload16(gB + (size_t)(it * 64) * KD + kt, &lB[(it * 64 + w * 8) * 64]);
    __syncthreads();
#pragma unroll
    for (int kc = 0; kc < 2; ++kc) {
      bf16x8 aF[4], bF[4];
#pragma unroll
      for (int f = 0; f < 4; ++f) {
        int r = wm * 64 + f * 16 + (l & 15);
        int ce = (kc * 32 + ((l >> 4) << 3)) ^ ((r & 7) << 3);
        aF[f] = *(const bf16x8*)(lA + r * 64 + ce);
      }
#pragma unroll
      for (int f = 0; f < 4; ++f) {
        int r = wn * 64 + f * 16 + (l & 15);
        int ce = (kc * 32 + ((l >> 4) << 3)) ^ ((r & 7) << 3);
        bF[f] = *(const bf16x8*)(lB + r * 64 + ce);
      }
#pragma unroll
      for (int mf = 0; mf < 4; ++mf)
#pragma unroll
        for (int nf = 0; nf < 4; ++nf)
          acc[mf][nf] = __builtin_amdgcn_mfma_f32_16x16x32_bf16(
              aF[mf], bF[nf], acc[mf][nf], 0, 0, 0);
    }
    __syncthreads();
  }

  const int lr = (l >> 4) << 2, lc = l & 15;
  // pass 1: v = acc + bias + resid -> xb; per-wave row partial sums
#pragma unroll
  for (int mf = 0; mf < 4; ++mf) {
#pragma unroll
    for (int jj = 0; jj < 4; ++jj) {
      int rowl = wm * 64 + mf * 16 + lr + jj;
      int row = m0 + rowl;
      float s = 0.f, q = 0.f;
#pragma unroll
      for (int nf = 0; nf < 4; ++nf) {
        int col = wn * 64 + nf * 16 + lc;
        float v = acc[mf][nf][jj] + bias[col] +
                  b2f(residb[(size_t)row * 256 + col]);
        acc[mf][nf][jj] = v;
        xbout[(size_t)row * 256 + col] = (short)f2bf(v);
        s += v;
        q += v * v;
      }
#pragma unroll
      for (int off = 1; off < 16; off <<= 1) {
        s += __shfl_xor(s, off);
        q += __shfl_xor(q, off);
      }
      if (lc == 0) {
        psum[wn][rowl] = s;
        psq[wn][rowl] = q;
      }
    }
  }
  __syncthreads();
  // pass 2: LN -> act bf16
#pragma unroll
  for (int mf = 0; mf < 4; ++mf) {
#pragma unroll
    for (int jj = 0; jj < 4; ++jj) {
      int rowl = wm * 64 + mf * 16 + lr + jj;
      int row = m0 + rowl;
      float S = psum[0][rowl] + psum[1][rowl] + psum[2][rowl] + psum[3][rowl];
      float Q = psq[0][rowl] + psq[1][rowl] + psq[2][rowl] + psq[3][rowl];
      float mean = S * (1.0f / 256.0f);
      float var = Q * (1.0f / 256.0f) - mean * mean;
      float rstd = rsqrtf(var + 1e-5f);
#pragma unroll
      for (int nf = 0; nf < 4; ++nf) {
        int col = wn * 64 + nf * 16 + lc;
        float v = (acc[mf][nf][jj] - mean) * rstd * lng[col] + lnb[col];
        actout[(size_t)row * 256 + col] = (short)f2bf(v);
      }
    }
  }
}

extern "C" void kernel_launch(void* const* d_in, const int* in_sizes, int n_in,
                              void* d_out, int out_size, void* d_ws, size_t ws_size,
                              hipStream_t stream) {
  const float* in_x   = (const float*)d_in[0];
  const int*   knn    = (const int*)d_in[1];
  const float* ln1_g  = (const float*)d_in[2];
  const float* ln1_b  = (const float*)d_in[3];
  const float* w_qkv  = (const float*)d_in[4];
  const float* w_proj = (const float*)d_in[5];
  const float* b_proj = (const float*)d_in[6];
  const float* ln2_g  = (const float*)d_in[7];
  const float* ln2_b  = (const float*)d_in[8];
  const float* w_fc1  = (const float*)d_in[9];
  const float* b_fc1  = (const float*)d_in[10];
  const float* w_fc2  = (const float*)d_in[11];
  const float* b_fc2  = (const float*)d_in[12];

  // Workspace layout (max ~198.3 MB):
  //   xb   [0,  32) MB   bf16 [N][256] residual stream
  //   act  [32, 64) MB   bf16 [N][256] (LN out / attn out)
  //   big  [64,192) MB   bf16 [N][1024] (fc1 out); sub-aliases during attn:
  //     q_bf [64,96)  k8 [96,112)  v8 [112,128)
  //   wT   [192,198.3) MB  transposed bf16 weights
  char* ws = (char*)d_ws;
  short* xb   = (short*)(ws);
  short* act  = (short*)(ws + 33554432);
  short* big  = (short*)(ws + 67108864);
  short* q_bf = big;
  uchar* k8   = (uchar*)(ws + 100663296);
  uchar* v8   = (uchar*)(ws + 117440512);
  short* wT   = (short*)(ws + 201326592);
  short* wqkvT  = wT;                // [L][768][256]
  short* wprojT = wT + 786432;       // [L][256][256]
  short* wfc1T  = wT + 1048576;      // [L][1024][256]
  short* wfc2T  = wT + 2097152;      // [L][256][1024]

  x2bf<<<16384, 256, 0, stream>>>(in_x, xb);
  wcast<<<dim3(768, 4), 256, 0, stream>>>(w_qkv, wqkvT, 256, 768);
  wcast<<<dim3(256, 4), 256, 0, stream>>>(w_proj, wprojT, 256, 256);
  wcast<<<dim3(1024, 4), 256, 0, stream>>>(w_fc1, wfc1T, 256, 1024);
  wcast<<<dim3(1024, 4), 256, 0, stream>>>(w_fc2, wfc2T, 1024, 256);

  ln_k<<<16384, 256, 0, stream>>>(xb, ln1_g, ln1_b, act);

  for (int i = 0; i < 4; ++i) {
    gemm_k<3, 256><<<3072, 256, 0, stream>>>(
        act, wqkvT + (size_t)i * 196608, nullptr, nullptr, q_bf, nullptr,
        k8, v8, 768, 6);
    attn_k<<<16384, 256, 0, stream>>>(q_bf, k8, v8, knn, act);
    // proj + resid + fused ln2 -> xb, act
    gemm_ln<256><<<512, 512, 0, stream>>>(
        act, wprojT + (size_t)i * 65536, b_proj + i * 256, xb, xb,
        ln2_g + i * 256, ln2_b + i * 256, act);
    gemm_k<2, 256><<<4096, 256, 0, stream>>>(
        act, wfc1T + (size_t)i * 262144, b_fc1 + i * 1024, nullptr, big,
        nullptr, nullptr, nullptr, 1024, 8);
    if (i < 3)
      // fc2 + resid + fused ln1(i+1) -> xb, act
      gemm_ln<1024><<<512, 512, 0, stream>>>(
          big, wfc2T + (size_t)i * 262144, b_fc2 + i * 256, xb, xb,
          ln1_g + (i + 1) * 256, ln1_b + (i + 1) * 256, act);
    else
      gemm_k<4, 1024><<<1024, 256, 0, stream>>>(
          big, wfc2T + (size_t)i * 262144, b_fc2 + i * 256, xb, nullptr,
          (float*)d_out, nullptr, nullptr, 256, 2);
  }
}

// Round 18
// 1087.358 us; speedup vs baseline: 1.0308x; 1.0308x over previous
//
#include <hip/hip_runtime.h>

typedef __attribute__((ext_vector_type(4))) float  f32x4;
typedef __attribute__((ext_vector_type(2))) float  f32x2;
typedef __attribute__((ext_vector_type(8))) __bf16 bf16x8;
typedef __attribute__((ext_vector_type(4))) short  s16x4;
typedef __attribute__((ext_vector_type(8))) short  s16x8;
typedef unsigned char uchar;

__device__ __forceinline__ unsigned short f2bf(float f) {
  unsigned u = __builtin_bit_cast(unsigned, f);
  u += 0x7FFFu + ((u >> 16) & 1u);
  return (unsigned short)(u >> 16);
}
__device__ __forceinline__ float b2f(short s) {
  return __builtin_bit_cast(float, (unsigned)((unsigned short)s) << 16);
}
// sigmoid-form gelu: ~4 VALU ops
__device__ __forceinline__ float gelu_sig(float v) {
  float t = __expf(-1.702f * v);
  return v * __builtin_amdgcn_rcpf(1.f + t);
}

__device__ __forceinline__ void gload16(const void* g, void* l) {
  __builtin_amdgcn_global_load_lds(
      (const __attribute__((address_space(1))) void*)g,
      (__attribute__((address_space(3))) void*)l, 16, 0, 0);
}

// in_x f32 -> xb bf16 (once; xb is the residual stream)
__global__ __launch_bounds__(256) void x2bf(const float* __restrict__ x,
                                            short* __restrict__ xb) {
  int i = blockIdx.x * 256 + threadIdx.x;
  float4 v = *(const float4*)(x + (size_t)i * 4);
  s16x4 o;
  o[0] = (short)f2bf(v.x);
  o[1] = (short)f2bf(v.y);
  o[2] = (short)f2bf(v.z);
  o[3] = (short)f2bf(v.w);
  *(s16x4*)(xb + (size_t)i * 4) = o;
}

// Transpose + cast weights: W [L][In][Out] f32 -> WT [L][Out][In] bf16
__global__ __launch_bounds__(256) void wcast(const float* __restrict__ W,
                                             short* __restrict__ WT,
                                             int In, int Out) {
  int i = blockIdx.x * 256 + threadIdx.x;
  int lay = blockIdx.y;
  if (i >= In * Out) return;
  const float* w = W + (size_t)lay * In * Out;
  short* wt = WT + (size_t)lay * In * Out;
  int ii = i % In, oo = i / In;
  wt[(size_t)oo * In + ii] = (short)f2bf(w[(size_t)ii * Out + oo]);
}

// LayerNorm over C=256, f32 in -> bf16 out (layer-0 ln1, reads in_x directly)
__global__ __launch_bounds__(256) void lnf_k(const float* __restrict__ x,
                                             const float* __restrict__ g,
                                             const float* __restrict__ b,
                                             short* __restrict__ out) {
  int row = blockIdx.x * 4 + (threadIdx.x >> 6);
  int l = threadIdx.x & 63;
  const float4 v = *(const float4*)(x + (size_t)row * 256 + l * 4);
  float s  = v.x + v.y + v.z + v.w;
  float ss = v.x * v.x + v.y * v.y + v.z * v.z + v.w * v.w;
#pragma unroll
  for (int o = 32; o >= 1; o >>= 1) {
    s  += __shfl_xor(s, o);
    ss += __shfl_xor(ss, o);
  }
  float mean = s * (1.0f / 256.0f);
  float var  = ss * (1.0f / 256.0f) - mean * mean;
  float rstd = rsqrtf(var + 1e-5f);
  const float4 gg = *(const float4*)(g + l * 4);
  const float4 bb = *(const float4*)(b + l * 4);
  s16x4 o4;
  o4[0] = (short)f2bf((v.x - mean) * rstd * gg.x + bb.x);
  o4[1] = (short)f2bf((v.y - mean) * rstd * gg.y + bb.y);
  o4[2] = (short)f2bf((v.z - mean) * rstd * gg.z + bb.z);
  o4[3] = (short)f2bf((v.w - mean) * rstd * gg.w + bb.w);
  *(s16x4*)(out + (size_t)row * 256 + l * 4) = o4;
}

// LayerNorm over C=256, bf16 in -> bf16 out, one wave per row
__global__ __launch_bounds__(256) void ln_k(const short* __restrict__ xb,
                                            const float* __restrict__ g,
                                            const float* __restrict__ b,
                                            short* __restrict__ out) {
  int row = blockIdx.x * 4 + (threadIdx.x >> 6);
  int l = threadIdx.x & 63;
  const s16x4 vb = *(const s16x4*)(xb + (size_t)row * 256 + l * 4);
  float v0 = b2f(vb[0]), v1 = b2f(vb[1]), v2 = b2f(vb[2]), v3 = b2f(vb[3]);
  float s  = v0 + v1 + v2 + v3;
  float ss = v0 * v0 + v1 * v1 + v2 * v2 + v3 * v3;
#pragma unroll
  for (int o = 32; o >= 1; o >>= 1) {
    s  += __shfl_xor(s, o);
    ss += __shfl_xor(ss, o);
  }
  float mean = s * (1.0f / 256.0f);
  float var  = ss * (1.0f / 256.0f) - mean * mean;
  float rstd = rsqrtf(var + 1e-5f);
  const float4 gg = *(const float4*)(g + l * 4);
  const float4 bb = *(const float4*)(b + l * 4);
  s16x4 o4;
  o4[0] = (short)f2bf((v0 - mean) * rstd * gg.x + bb.x);
  o4[1] = (short)f2bf((v1 - mean) * rstd * gg.y + bb.y);
  o4[2] = (short)f2bf((v2 - mean) * rstd * gg.z + bb.z);
  o4[3] = (short)f2bf((v3 - mean) * rstd * gg.w + bb.w);
  *(s16x4*)(out + (size_t)row * 256 + l * 4) = o4;
}

// KNN attention: one wave per point. q bf16 [N][256], k8/v8 fp8 [N][256]
__global__ __launch_bounds__(256) void attn_k(const short* __restrict__ q_,
                                              const uchar* __restrict__ k8,
                                              const uchar* __restrict__ v8,
                                              const int* __restrict__ knn,
                                              short* __restrict__ out) {
  int n = blockIdx.x * 4 + (threadIdx.x >> 6);
  int l = threadIdx.x & 63;
  int j = l & 15, g = l >> 4;
  int idxj = knn[(size_t)n * 16 + j];
  const short* qp = q_ + (size_t)n * 256 + g * 64;
  const uchar* kp = k8 + (size_t)idxj * 256 + g * 64;
  float partial = 0.f;
#pragma unroll
  for (int t = 0; t < 4; ++t) {  // 16 channels per t
    int4 kv = *(const int4*)(kp + t * 16);
    s16x8 q0 = *(const s16x8*)(qp + t * 16);
    s16x8 q1 = *(const s16x8*)(qp + t * 16 + 8);
    f32x2 a;
    a = __builtin_amdgcn_cvt_pk_f32_fp8(kv.x, false);
    partial += a[0] * b2f(q0[0]) + a[1] * b2f(q0[1]);
    a = __builtin_amdgcn_cvt_pk_f32_fp8(kv.x, true);
    partial += a[0] * b2f(q0[2]) + a[1] * b2f(q0[3]);
    a = __builtin_amdgcn_cvt_pk_f32_fp8(kv.y, false);
    partial += a[0] * b2f(q0[4]) + a[1] * b2f(q0[5]);
    a = __builtin_amdgcn_cvt_pk_f32_fp8(kv.y, true);
    partial += a[0] * b2f(q0[6]) + a[1] * b2f(q0[7]);
    a = __builtin_amdgcn_cvt_pk_f32_fp8(kv.z, false);
    partial += a[0] * b2f(q1[0]) + a[1] * b2f(q1[1]);
    a = __builtin_amdgcn_cvt_pk_f32_fp8(kv.z, true);
    partial += a[0] * b2f(q1[2]) + a[1] * b2f(q1[3]);
    a = __builtin_amdgcn_cvt_pk_f32_fp8(kv.w, false);
    partial += a[0] * b2f(q1[4]) + a[1] * b2f(q1[5]);
    a = __builtin_amdgcn_cvt_pk_f32_fp8(kv.w, true);
    partial += a[0] * b2f(q1[6]) + a[1] * b2f(q1[7]);
  }
  partial += __shfl_xor(partial, 16);
  partial += __shfl_xor(partial, 32);
  float score = partial * 0.0625f;  // C^-0.5, C=256
  float mx = score;
#pragma unroll
  for (int o = 1; o < 16; o <<= 1) mx = fmaxf(mx, __shfl_xor(mx, o));
  float e = __expf(score - mx);
  float sum = e;
#pragma unroll
  for (int o = 1; o < 16; o <<= 1) sum += __shfl_xor(sum, o);
  float attn = e / sum;
  float4 o4 = {0.f, 0.f, 0.f, 0.f};
#pragma unroll
  for (int jj = 0; jj < 16; ++jj) {
    float aj = __shfl(attn, jj);
    int   ij = __shfl(idxj, jj);
    int vv = *(const int*)(v8 + (size_t)ij * 256 + l * 4);
    f32x2 lo = __builtin_amdgcn_cvt_pk_f32_fp8(vv, false);
    f32x2 hi = __builtin_amdgcn_cvt_pk_f32_fp8(vv, true);
    o4.x += aj * lo[0];
    o4.y += aj * lo[1];
    o4.z += aj * hi[0];
    o4.w += aj * hi[1];
  }
  s16x4 ob;
  ob[0] = (short)f2bf(o4.x);
  ob[1] = (short)f2bf(o4.y);
  ob[2] = (short)f2bf(o4.z);
  ob[3] = (short)f2bf(o4.w);
  *(s16x4*)(out + (size_t)n * 256 + l * 4) = ob;
}

// GEMM: A [M][KD] bf16 x BT [Nout][KD] bf16 -> out [M][Nout]
// EPI 1: +bias +resid(bf16) -> bf16 xb.  EPI 4: +bias +resid(bf16) -> f32.
// EPI 2: +bias, sigmoid-gelu -> bf16 (LDS-transpose, s16x8 stores).
// EPI 3: qkv split -> q bf16 / k8 fp8 / v8 fp8 (LDS-transpose epilogue).
// 128x128 tile, BK=64, 4 waves (2x2), T2 XOR swizzle, T1 XCD-chunked swizzle.
template <int EPI, int KD>
__global__ __launch_bounds__(256) void gemm_k(
    const short* __restrict__ A, const short* __restrict__ BT,
    const float* __restrict__ bias, const short* __restrict__ residb,
    short* __restrict__ outb, float* __restrict__ outf,
    uchar* __restrict__ k8, uchar* __restrict__ v8, int Nout, int gx) {
  __shared__ __align__(16) char pool[36864];
  short* lA = (short*)pool;
  short* lB = (short*)(pool + 16384);
  const int tid = threadIdx.x;
  const int l = tid & 63, w = tid >> 6;
  const int nwg = gridDim.x;
  const int bid = blockIdx.x;
  const int swz = (bid & 7) * (nwg >> 3) + (bid >> 3);
  const int m0 = (swz / gx) << 7, n0 = (swz % gx) << 7;
  const int wm = w >> 1, wn = w & 1;

  f32x4 acc[4][4];
#pragma unroll
  for (int i = 0; i < 4; ++i)
#pragma unroll
    for (int jj = 0; jj < 4; ++jj) acc[i][jj] = f32x4{0.f, 0.f, 0.f, 0.f};

  const int srow = (w << 3) + (l >> 3);
  const int scol = (((l & 7) << 3)) ^ ((srow & 7) << 3);
  const short* gA = A + (size_t)(m0 + srow) * KD + scol;
  const short* gB = BT + (size_t)(n0 + srow) * KD + scol;

  for (int kt = 0; kt < KD; kt += 64) {
#pragma unroll
    for (int it = 0; it < 4; ++it) {
      gload16(gA + (size_t)(it * 32) * KD + kt, &lA[(it * 32 + w * 8) * 64]);
      gload16(gB + (size_t)(it * 32) * KD + kt, &lB[(it * 32 + w * 8) * 64]);
    }
    __syncthreads();
#pragma unroll
    for (int kc = 0; kc < 2; ++kc) {
      bf16x8 aF[4], bF[4];
#pragma unroll
      for (int f = 0; f < 4; ++f) {
        int r = wm * 64 + f * 16 + (l & 15);
        int ce = (kc * 32 + ((l >> 4) << 3)) ^ ((r & 7) << 3);
        aF[f] = *(const bf16x8*)(lA + r * 64 + ce);
      }
#pragma unroll
      for (int f = 0; f < 4; ++f) {
        int r = wn * 64 + f * 16 + (l & 15);
        int ce = (kc * 32 + ((l >> 4) << 3)) ^ ((r & 7) << 3);
        bF[f] = *(const bf16x8*)(lB + r * 64 + ce);
      }
#pragma unroll
      for (int mf = 0; mf < 4; ++mf)
#pragma unroll
        for (int nf = 0; nf < 4; ++nf)
          acc[mf][nf] = __builtin_amdgcn_mfma_f32_16x16x32_bf16(
              aF[mf], bF[nf], acc[mf][nf], 0, 0, 0);
    }
    __syncthreads();
  }

  const int lr = (l >> 4) << 2, lc = l & 15;
  if (EPI == 1 || EPI == 4) {
#pragma unroll
    for (int mf = 0; mf < 4; ++mf) {
#pragma unroll
      for (int nf = 0; nf < 4; ++nf) {
#pragma unroll
        for (int jj = 0; jj < 4; ++jj) {
          int row = m0 + wm * 64 + mf * 16 + lr + jj;
          int col = n0 + wn * 64 + nf * 16 + lc;
          float v = acc[mf][nf][jj] + bias[col] +
                    b2f(residb[(size_t)row * 256 + col]);
          if (EPI == 1)
            outb[(size_t)row * 256 + col] = (short)f2bf(v);
          else
            outf[(size_t)row * 256 + col] = v;
        }
      }
    }
    return;
  }

  // EPI 2/3: wave-private LDS transpose -> coalesced stores.
  short* myL = (short*)(pool + w * 9216);
#pragma unroll
  for (int mf = 0; mf < 4; ++mf) {
#pragma unroll
    for (int nf = 0; nf < 4; ++nf) {
#pragma unroll
      for (int jj = 0; jj < 4; ++jj) {
        int rl = mf * 16 + lr + jj;
        int cl = nf * 16 + lc;
        float v = acc[mf][nf][jj];
        if (EPI == 2) v = gelu_sig(v + bias[n0 + wn * 64 + cl]);
        myL[rl * 72 + cl] = (short)f2bf(v);
      }
    }
  }
#pragma unroll
  for (int it = 0; it < 8; ++it) {
    int rl = it * 8 + (l >> 3);
    int cl = (l & 7) * 8;
    s16x8 vv = *(const s16x8*)(myL + rl * 72 + cl);
    int rowg = m0 + wm * 64 + rl;
    int colg = n0 + wn * 64 + cl;
    if (EPI == 2) {
      *(s16x8*)(outb + (size_t)rowg * Nout + colg) = vv;
    } else {  // EPI 3: qkv split
      if (colg < 256) {
        *(s16x8*)(outb + (size_t)rowg * 256 + colg) = vv;
      } else {
        unsigned w0 = __builtin_amdgcn_cvt_pk_fp8_f32(b2f(vv[0]), b2f(vv[1]), 0, false);
        w0 = __builtin_amdgcn_cvt_pk_fp8_f32(b2f(vv[2]), b2f(vv[3]), w0, true);
        unsigned w1 = __builtin_amdgcn_cvt_pk_fp8_f32(b2f(vv[4]), b2f(vv[5]), 0, false);
        w1 = __builtin_amdgcn_cvt_pk_fp8_f32(b2f(vv[6]), b2f(vv[7]), w1, true);
        int2 pk = make_int2((int)w0, (int)w1);
        uchar* dst = (colg < 512) ? (k8 + (size_t)rowg * 256 + (colg - 256))
                                  : (v8 + (size_t)rowg * 256 + (colg - 512));
        *(int2*)dst = pk;
      }
    }
  }
}

extern "C" void kernel_launch(void* const* d_in, const int* in_sizes, int n_in,
                              void* d_out, int out_size, void* d_ws, size_t ws_size,
                              hipStream_t stream) {
  const float* in_x   = (const float*)d_in[0];
  const int*   knn    = (const int*)d_in[1];
  const float* ln1_g  = (const float*)d_in[2];
  const float* ln1_b  = (const float*)d_in[3];
  const float* w_qkv  = (const float*)d_in[4];
  const float* w_proj = (const float*)d_in[5];
  const float* b_proj = (const float*)d_in[6];
  const float* ln2_g  = (const float*)d_in[7];
  const float* ln2_b  = (const float*)d_in[8];
  const float* w_fc1  = (const float*)d_in[9];
  const float* b_fc1  = (const float*)d_in[10];
  const float* w_fc2  = (const float*)d_in[11];
  const float* b_fc2  = (const float*)d_in[12];

  // Workspace layout (max ~198.3 MB):
  //   xb   [0,  32) MB   bf16 [N][256] residual stream
  //   act  [32, 64) MB   bf16 [N][256] (LN out / attn out)
  //   big  [64,192) MB   bf16 [N][1024] (fc1 out); sub-aliases during attn:
  //     q_bf [64,96)  k8 [96,112)  v8 [112,128)
  //   wT   [192,198.3) MB  transposed bf16 weights
  char* ws = (char*)d_ws;
  short* xb   = (short*)(ws);
  short* act  = (short*)(ws + 33554432);
  short* big  = (short*)(ws + 67108864);
  short* q_bf = big;
  uchar* k8   = (uchar*)(ws + 100663296);
  uchar* v8   = (uchar*)(ws + 117440512);
  short* wT   = (short*)(ws + 201326592);
  short* wqkvT  = wT;                // [L][768][256]
  short* wprojT = wT + 786432;       // [L][256][256]
  short* wfc1T  = wT + 1048576;      // [L][1024][256]
  short* wfc2T  = wT + 2097152;      // [L][256][1024]

  x2bf<<<16384, 256, 0, stream>>>(in_x, xb);
  wcast<<<dim3(768, 4), 256, 0, stream>>>(w_qkv, wqkvT, 256, 768);
  wcast<<<dim3(256, 4), 256, 0, stream>>>(w_proj, wprojT, 256, 256);
  wcast<<<dim3(1024, 4), 256, 0, stream>>>(w_fc1, wfc1T, 256, 1024);
  wcast<<<dim3(1024, 4), 256, 0, stream>>>(w_fc2, wfc2T, 1024, 256);

  for (int i = 0; i < 4; ++i) {
    if (i == 0)
      lnf_k<<<16384, 256, 0, stream>>>(in_x, ln1_g, ln1_b, act);
    else
      ln_k<<<16384, 256, 0, stream>>>(xb, ln1_g + i * 256, ln1_b + i * 256, act);
    gemm_k<3, 256><<<3072, 256, 0, stream>>>(
        act, wqkvT + (size_t)i * 196608, nullptr, nullptr, q_bf, nullptr,
        k8, v8, 768, 6);
    attn_k<<<16384, 256, 0, stream>>>(q_bf, k8, v8, knn, act);
    gemm_k<1, 256><<<1024, 256, 0, stream>>>(
        act, wprojT + (size_t)i * 65536, b_proj + i * 256, xb, xb,
        nullptr, nullptr, nullptr, 256, 2);
    ln_k<<<16384, 256, 0, stream>>>(xb, ln2_g + i * 256, ln2_b + i * 256, act);
    gemm_k<2, 256><<<4096, 256, 0, stream>>>(
        act, wfc1T + (size_t)i * 262144, b_fc1 + i * 1024, nullptr, big,
        nullptr, nullptr, nullptr, 1024, 8);
    if (i < 3)
      gemm_k<1, 1024><<<1024, 256, 0, stream>>>(
          big, wfc2T + (size_t)i * 262144, b_fc2 + i * 256, xb, xb,
          nullptr, nullptr, nullptr, 256, 2);
    else
      gemm_k<4, 1024><<<1024, 256, 0, stream>>>(
          big, wfc2T + (size_t)i * 262144, b_fc2 + i * 256, xb, nullptr,
          (float*)d_out, nullptr, nullptr, 256, 2);
  }
}